// Round 1
// baseline (1565.059 us; speedup 1.0000x reference)
//
#include <hip/hip_runtime.h>
#include <cstdint>
#include <cstddef>

// Problem constants
#define DIMK 1024
#define FFNK 4096
#define NEXP 10
#define NTOK 8192
#define MAXTILES 74   // sum_e ceil(m_e/128) <= floor((8192+10*127)/128) = 73

typedef __attribute__((ext_vector_type(8))) short s16x8;
typedef __attribute__((ext_vector_type(8))) unsigned short u16x8;
typedef __attribute__((ext_vector_type(4))) float f32x4;

__device__ __forceinline__ unsigned short f2bf(float f) {
  unsigned int u = __float_as_uint(f);
  unsigned int r = u + 0x7fffu + ((u >> 16) & 1u);   // RNE
  return (unsigned short)(r >> 16);
}
__device__ __forceinline__ float bf2f(unsigned short s) {
  return __uint_as_float(((unsigned int)s) << 16);
}

__device__ __forceinline__ void gload16(const unsigned short* gp, unsigned short* lp) {
  __builtin_amdgcn_global_load_lds(
      (const __attribute__((address_space(1))) void*)gp,
      (__attribute__((address_space(3))) void*)lp, 16, 0, 0);
}

// ---------------- prep kernels ----------------

__global__ void k_prep0(int* meta) {            // zero counts/cursor/tile_count
  if (threadIdx.x < 48) meta[threadIdx.x] = 0;
}

__global__ void k_count(const int* __restrict__ dom, int* __restrict__ counts) {
  int i = blockIdx.x * 256 + threadIdx.x;
  atomicAdd(&counts[dom[i]], 1);
}

__global__ void k_scan(const int* __restrict__ counts, int* __restrict__ cursor,
                       int4* __restrict__ tiles, int* __restrict__ tcnt) {
  if (threadIdx.x == 0 && blockIdx.x == 0) {
    int off = 0, t = 0;
    for (int e = 0; e < NEXP; ++e) {
      int c = counts[e];
      cursor[e] = off;
      for (int s = 0; s < c; s += 128)
        tiles[t++] = make_int4(off + s, (c - s < 128 ? c - s : 128), e, 0);
      off += c;
    }
    *tcnt = t;
  }
}

__global__ void k_scatter(const int* __restrict__ dom, int* __restrict__ cursor,
                          int* __restrict__ perm) {
  int i = blockIdx.x * 256 + threadIdx.x;
  int p = atomicAdd(&cursor[dom[i]], 1);
  perm[p] = i;
}

__global__ void k_cvt(const float* __restrict__ x, unsigned short* __restrict__ xb) {
  int i = blockIdx.x * 256 + threadIdx.x;            // 8 floats per thread
  const float4* xv = (const float4*)x;
  float4 a = xv[2 * i], b = xv[2 * i + 1];
  u16x8 o;
  o[0] = f2bf(a.x); o[1] = f2bf(a.y); o[2] = f2bf(a.z); o[3] = f2bf(a.w);
  o[4] = f2bf(b.x); o[5] = f2bf(b.y); o[6] = f2bf(b.z); o[7] = f2bf(b.w);
  *(u16x8*)(xb + 8 * i) = o;
}

// ---------------- fused GEMM ----------------
// C[128x128] per block, BK=32, 4 waves (2x2), 16x16x32 bf16 MFMA.
// A: bf16 activations (global_load_lds, per-lane gather through perm if GATHER_A).
// B: fp32 weights [K][Nw], reg-staged + converted to bf16, kb-major LDS layout.
// EPI: 0 = gelu -> bf16 (h1), 1 = sigmoid -> bf16 (g), 2 = out = x + g*(acc+b2).

enum { EPI_GELU = 0, EPI_SIG = 1, EPI_OUT = 2 };

template<int EPI, bool GROUPED, bool GATHER_A, bool GATHER_OUT, bool ACCUM>
__global__ __launch_bounds__(256)
void gemm_k(const unsigned short* __restrict__ A, int lda, int Ktot,
            const float* __restrict__ Bw, const float* __restrict__ bias, int Nw,
            const float* __restrict__ X, const unsigned short* __restrict__ G,
            void* __restrict__ OutP,
            const int* __restrict__ perm, const int4* __restrict__ tiles,
            const int* __restrict__ tile_count)
{
  __shared__ unsigned short Asm[128 * 32];      // [row][k] row-major, 8KB
  __shared__ unsigned short Bsm[4 * 128 * 8];   // [kb][col][e] kb-major, 8KB

  int row0, rowcnt, expert;
  if constexpr (GROUPED) {
    if ((int)blockIdx.x >= *tile_count) return;
    int4 te = tiles[blockIdx.x];
    row0 = te.x; rowcnt = te.y; expert = te.z;
  } else {
    row0 = blockIdx.x * 128; rowcnt = 128; expert = 0;
  }

  const int tid = threadIdx.x;
  const int wave = tid >> 6, lane = tid & 63;
  const int wm = wave >> 1, wn = wave & 1;
  const int ncol0 = blockIdx.y * 128;
  const int la = lane & 15, hb = lane >> 4;

  const float* Bx = Bw + (size_t)expert * Ktot * Nw;
  const float* bi = bias + (size_t)expert * Nw;

  // A staging: per wave 2 segments of 16 rows; lane -> (row_in_seg = l>>2, chunk = l&3)
  const unsigned short* ap0;
  const unsigned short* ap1;
  {
    int rl = lane >> 2, ch = lane & 3;
    int lrow0 = (wave * 2 + 0) * 16 + rl;
    int lrow1 = (wave * 2 + 1) * 16 + rl;
    int ar0 = row0 + (GROUPED ? (lrow0 < rowcnt ? lrow0 : rowcnt - 1) : lrow0);
    int ar1 = row0 + (GROUPED ? (lrow1 < rowcnt ? lrow1 : rowcnt - 1) : lrow1);
    int arow0 = GATHER_A ? perm[ar0] : ar0;
    int arow1 = GATHER_A ? perm[ar1] : ar1;
    ap0 = A + (size_t)arow0 * lda + ch * 8;
    ap1 = A + (size_t)arow1 * lda + ch * 8;
  }
  unsigned short* AsmDst0 = Asm + (wave * 2 + 0) * 512;
  unsigned short* AsmDst1 = Asm + (wave * 2 + 1) * 512;

  // B staging: thread -> (col = tid&127, khalf = tid>>7), 16 fp32 column loads
  const int bcol = tid & 127, kh = tid >> 7;
  const float* Bcol = Bx + (size_t)(kh * 16) * Nw + ncol0 + bcol;
  unsigned short* BsmW0 = Bsm + (2 * kh) * 1024 + bcol * 8;
  unsigned short* BsmW1 = BsmW0 + 1024;

  f32x4 acc[4][4];
#pragma unroll
  for (int m = 0; m < 4; ++m)
#pragma unroll
    for (int n = 0; n < 4; ++n) acc[m][n] = (f32x4){0.f, 0.f, 0.f, 0.f};

  for (int k0 = 0; k0 < Ktot; k0 += 32) {
    float bv[16];
#pragma unroll
    for (int i = 0; i < 16; ++i) bv[i] = Bcol[(k0 + i) * Nw];

    __syncthreads();   // previous tile's LDS reads complete

    gload16(ap0 + k0, AsmDst0);
    gload16(ap1 + k0, AsmDst1);

    u16x8 blo, bhi;
#pragma unroll
    for (int i = 0; i < 8; ++i) { blo[i] = f2bf(bv[i]); bhi[i] = f2bf(bv[i + 8]); }
    *(u16x8*)BsmW0 = blo;
    *(u16x8*)BsmW1 = bhi;

    __syncthreads();   // drains vmcnt (global_load_lds) + lgkm (ds_write)

    s16x8 af[4], bfv[4];
#pragma unroll
    for (int m = 0; m < 4; ++m)
      af[m] = *(const s16x8*)(Asm + (wm * 64 + m * 16 + la) * 32 + hb * 8);
#pragma unroll
    for (int n = 0; n < 4; ++n)
      bfv[n] = *(const s16x8*)(Bsm + hb * 1024 + (wn * 64 + n * 16 + la) * 8);
#pragma unroll
    for (int m = 0; m < 4; ++m)
#pragma unroll
      for (int n = 0; n < 4; ++n)
        acc[m][n] = __builtin_amdgcn_mfma_f32_16x16x32_bf16(af[m], bfv[n], acc[m][n], 0, 0, 0);
  }

  // Epilogue. C/D layout: col = lane&15, row = (lane>>4)*4 + j  [m89-verified]
#pragma unroll
  for (int m = 0; m < 4; ++m) {
#pragma unroll
    for (int n = 0; n < 4; ++n) {
      int gcol = ncol0 + wn * 64 + n * 16 + la;
      float bcst = bi[gcol];
#pragma unroll
      for (int j = 0; j < 4; ++j) {
        int lrow = wm * 64 + m * 16 + (hb << 2) + j;
        if (GROUPED && lrow >= rowcnt) continue;
        int prow = row0 + lrow;
        float v = acc[m][n][j] + bcst;
        if constexpr (EPI == EPI_GELU) {
          float ge = 0.5f * v * (1.0f + erff(v * 0.70710678118654752f));
          ((unsigned short*)OutP)[(size_t)prow * Nw + gcol] = f2bf(ge);
        } else if constexpr (EPI == EPI_SIG) {
          float s = 1.0f / (1.0f + expf(-v));
          ((unsigned short*)OutP)[(size_t)prow * Nw + gcol] = f2bf(s);
        } else {
          int orow = GATHER_OUT ? perm[prow] : prow;
          float gf = bf2f(G[(size_t)prow * Nw + gcol]);
          float xv = X[(size_t)orow * Nw + gcol];
          float res = xv + gf * v;
          float* op = (float*)OutP + (size_t)orow * Nw + gcol;
          if constexpr (ACCUM) *op += res; else *op = res;
        }
      }
    }
  }
}

// ---------------- launcher ----------------
// ws layout (bytes):
//   [0,   16MB)  xb : x as bf16            8192*1024*2
//   [16MB,80MB)  h1 : gelu output bf16     8192*4096*2   (reused shared->domain)
//   [80MB,96MB)  g  : gate bf16            8192*1024*2   (reused shared->domain)
//   [96MB, +34KB) meta: counts[16] cursor[16] tcnt[16] tiles[80]*int4 perm[8192]
// total ~96.04 MB

extern "C" void kernel_launch(void* const* d_in, const int* in_sizes, int n_in,
                              void* d_out, int out_size, void* d_ws, size_t ws_size,
                              hipStream_t stream) {
  const float* x   = (const float*)d_in[0];
  const int*   dom = (const int*)d_in[1];
  const float* sW1 = (const float*)d_in[2];
  const float* sb1 = (const float*)d_in[3];
  const float* sW2 = (const float*)d_in[4];
  const float* sb2 = (const float*)d_in[5];
  const float* sWg = (const float*)d_in[6];
  const float* sbg = (const float*)d_in[7];
  const float* dW1 = (const float*)d_in[8];
  const float* db1 = (const float*)d_in[9];
  const float* dW2 = (const float*)d_in[10];
  const float* db2 = (const float*)d_in[11];
  const float* dWg = (const float*)d_in[12];
  const float* dbg = (const float*)d_in[13];
  float* out = (float*)d_out;

  uint8_t* ws = (uint8_t*)d_ws;
  unsigned short* xb = (unsigned short*)ws;
  unsigned short* h1 = (unsigned short*)(ws + (size_t)16 * 1024 * 1024);
  unsigned short* g  = (unsigned short*)(ws + (size_t)80 * 1024 * 1024);
  int* meta   = (int*)(ws + (size_t)96 * 1024 * 1024);
  int* counts = meta;
  int* cursor = meta + 16;
  int* tcnt   = meta + 32;
  int4* tiles = (int4*)(meta + 48);          // 16B-aligned (192B offset)
  int* perm   = meta + 48 + 4 * 80;

  k_prep0  <<<1, 64, 0, stream>>>(meta);
  k_count  <<<NTOK / 256, 256, 0, stream>>>(dom, counts);
  k_scan   <<<1, 1, 0, stream>>>(counts, cursor, tiles, tcnt);
  k_scatter<<<NTOK / 256, 256, 0, stream>>>(dom, cursor, perm);
  k_cvt    <<<NTOK * DIMK / 8 / 256, 256, 0, stream>>>(x, xb);

  dim3 blk(256);
  // shared expert (dense, M = 8192)
  gemm_k<EPI_GELU, false, false, false, false><<<dim3(64, 32), blk, 0, stream>>>(
      xb, DIMK, DIMK, sW1, sb1, FFNK, nullptr, nullptr, h1, nullptr, nullptr, nullptr);
  gemm_k<EPI_SIG, false, false, false, false><<<dim3(64, 8), blk, 0, stream>>>(
      xb, DIMK, DIMK, sWg, sbg, DIMK, nullptr, nullptr, g, nullptr, nullptr, nullptr);
  gemm_k<EPI_OUT, false, false, false, false><<<dim3(64, 8), blk, 0, stream>>>(
      h1, FFNK, FFNK, sW2, sb2, DIMK, x, g, out, nullptr, nullptr, nullptr);
  // domain experts (grouped via tile table, rows gathered through perm)
  gemm_k<EPI_GELU, true, true, false, false><<<dim3(MAXTILES, 32), blk, 0, stream>>>(
      xb, DIMK, DIMK, dW1, db1, FFNK, nullptr, nullptr, h1, perm, tiles, tcnt);
  gemm_k<EPI_SIG, true, true, false, false><<<dim3(MAXTILES, 8), blk, 0, stream>>>(
      xb, DIMK, DIMK, dWg, dbg, DIMK, nullptr, nullptr, g, perm, tiles, tcnt);
  gemm_k<EPI_OUT, true, false, true, true><<<dim3(MAXTILES, 8), blk, 0, stream>>>(
      h1, FFNK, FFNK, dW2, db2, DIMK, x, g, out, perm, tiles, tcnt);
}

// Round 2
// 1248.500 us; speedup vs baseline: 1.2536x; 1.2536x over previous
//
#include <hip/hip_runtime.h>
#include <cstdint>
#include <cstddef>

// Problem constants
#define DIMK 1024
#define FFNK 4096
#define NEXP 10
#define NTOK 8192
#define MAXTILES 74   // sum_e ceil(m_e/128) <= 73

typedef __attribute__((ext_vector_type(8))) short s16x8;
typedef __attribute__((ext_vector_type(8))) unsigned short u16x8;
typedef __attribute__((ext_vector_type(4))) float f32x4;

__device__ __forceinline__ unsigned short f2bf(float f) {
  unsigned int u = __float_as_uint(f);
  unsigned int r = u + 0x7fffu + ((u >> 16) & 1u);   // RNE
  return (unsigned short)(r >> 16);
}
__device__ __forceinline__ float bf2f(unsigned short s) {
  return __uint_as_float(((unsigned int)s) << 16);
}

__device__ __forceinline__ void gload16(const unsigned short* gp, unsigned short* lp) {
  __builtin_amdgcn_global_load_lds(
      (const __attribute__((address_space(1))) void*)gp,
      (__attribute__((address_space(3))) void*)lp, 16, 0, 0);
}

// ---------------- prep kernels ----------------

__global__ void k_prep0(int* meta) {            // zero counts/cursor/tile_count
  if (threadIdx.x < 48) meta[threadIdx.x] = 0;
}

__global__ void k_count(const int* __restrict__ dom, int* __restrict__ counts) {
  int i = blockIdx.x * 256 + threadIdx.x;
  atomicAdd(&counts[dom[i]], 1);
}

__global__ void k_scan(const int* __restrict__ counts, int* __restrict__ cursor,
                       int4* __restrict__ tiles, int* __restrict__ tcnt) {
  if (threadIdx.x == 0 && blockIdx.x == 0) {
    int off = 0, t = 0;
    for (int e = 0; e < NEXP; ++e) {
      int c = counts[e];
      cursor[e] = off;
      for (int s = 0; s < c; s += 128)
        tiles[t++] = make_int4(off + s, (c - s < 128 ? c - s : 128), e, 0);
      off += c;
    }
    *tcnt = t;
  }
}

__global__ void k_scatter(const int* __restrict__ dom, int* __restrict__ cursor,
                          int* __restrict__ perm) {
  int i = blockIdx.x * 256 + threadIdx.x;
  int p = atomicAdd(&cursor[dom[i]], 1);
  perm[p] = i;
}

__global__ void k_cvt(const float* __restrict__ x, unsigned short* __restrict__ xb) {
  int i = blockIdx.x * 256 + threadIdx.x;            // 8 floats per thread
  const float4* xv = (const float4*)x;
  float4 a = xv[2 * i], b = xv[2 * i + 1];
  u16x8 o;
  o[0] = f2bf(a.x); o[1] = f2bf(a.y); o[2] = f2bf(a.z); o[3] = f2bf(a.w);
  o[4] = f2bf(b.x); o[5] = f2bf(b.y); o[6] = f2bf(b.z); o[7] = f2bf(b.w);
  *(u16x8*)(xb + 8 * i) = o;
}

// transpose + fp32->bf16: in [E][K][N] fp32 -> out [E][N][K] bf16
// grid (K/64, N/64, E), block 256. LDS 64x65 ushort (pad -> conflict-free).
__global__ __launch_bounds__(256)
void k_cvtT(const float* __restrict__ in, unsigned short* __restrict__ outp,
            int K, int N) {
  __shared__ unsigned short t[64][65];
  const float* src = in + (size_t)blockIdx.z * K * N;
  unsigned short* dst = outp + (size_t)blockIdx.z * K * N;
  int k0 = blockIdx.x * 64, n0 = blockIdx.y * 64;
  int tr = threadIdx.x >> 4;          // 0..15
  int tc = (threadIdx.x & 15) * 4;    // 0..60
#pragma unroll
  for (int i = 0; i < 4; ++i) {
    int k = tr + i * 16;
    float4 v = *(const float4*)(src + (size_t)(k0 + k) * N + n0 + tc);
    t[k][tc + 0] = f2bf(v.x); t[k][tc + 1] = f2bf(v.y);
    t[k][tc + 2] = f2bf(v.z); t[k][tc + 3] = f2bf(v.w);
  }
  __syncthreads();
#pragma unroll
  for (int i = 0; i < 4; ++i) {
    int n = tr + i * 16;
    ushort4 o;
    o.x = t[tc + 0][n]; o.y = t[tc + 1][n];
    o.z = t[tc + 2][n]; o.w = t[tc + 3][n];
    *(ushort4*)(dst + (size_t)(n0 + n) * K + k0 + tc) = o;
  }
}

// ---------------- fused GEMM (m97 structure) ----------------
// C[128x128] per block, BK=32, 4 waves (2x2), 16x16x32 bf16 MFMA.
// A: bf16 [M][Ktot] (global_load_lds, gather through perm if GATHER_A).
// B: bf16 TRANSPOSED [Nw][Ktot] (global_load_lds) — symmetric with A.
// EPI: 0 = gelu -> bf16 (h1), 1 = sigmoid -> bf16 (g), 2 = out = x + g*(acc+b2).

enum { EPI_GELU = 0, EPI_SIG = 1, EPI_OUT = 2 };

template<int EPI, bool GROUPED, bool GATHER_A, bool GATHER_OUT, bool ACCUM>
__global__ __launch_bounds__(256)
void gemm_k(const unsigned short* __restrict__ A, int lda, int Ktot,
            const unsigned short* __restrict__ Bt, const float* __restrict__ bias, int Nw,
            const float* __restrict__ X, const unsigned short* __restrict__ G,
            void* __restrict__ OutP,
            const int* __restrict__ perm, const int4* __restrict__ tiles,
            const int* __restrict__ tile_count)
{
  __shared__ unsigned short Asm[128 * 32];      // [row][k] row-major, 8KB
  __shared__ unsigned short Bsm[128 * 32];      // [col][k] row-major, 8KB

  int row0, rowcnt, expert;
  if constexpr (GROUPED) {
    if ((int)blockIdx.x >= *tile_count) return;
    int4 te = tiles[blockIdx.x];
    row0 = te.x; rowcnt = te.y; expert = te.z;
  } else {
    row0 = blockIdx.x * 128; rowcnt = 128; expert = 0;
  }

  const int tid = threadIdx.x;
  const int wave = tid >> 6, lane = tid & 63;
  const int wm = wave >> 1, wn = wave & 1;
  const int ncol0 = blockIdx.y * 128;
  const int la = lane & 15, hb = lane >> 4;

  const unsigned short* Bx = Bt + (size_t)expert * Ktot * Nw;   // [Nw][Ktot]
  const float* bi = bias + (size_t)expert * Nw;

  // Staging: per wave 2 segments of 16 rows; lane -> (row_in_seg = l>>2, chunk16B = l&3)
  const int rl = lane >> 2, ch = lane & 3;
  const int lrow0 = (wave * 2 + 0) * 16 + rl;
  const int lrow1 = (wave * 2 + 1) * 16 + rl;

  const unsigned short *apA0, *apA1;
  {
    int ar0 = row0 + (GROUPED ? (lrow0 < rowcnt ? lrow0 : rowcnt - 1) : lrow0);
    int ar1 = row0 + (GROUPED ? (lrow1 < rowcnt ? lrow1 : rowcnt - 1) : lrow1);
    int arow0 = GATHER_A ? perm[ar0] : ar0;
    int arow1 = GATHER_A ? perm[ar1] : ar1;
    apA0 = A + (size_t)arow0 * lda + ch * 8;
    apA1 = A + (size_t)arow1 * lda + ch * 8;
  }
  const unsigned short* bp0 = Bx + (size_t)(ncol0 + lrow0) * Ktot + ch * 8;
  const unsigned short* bp1 = Bx + (size_t)(ncol0 + lrow1) * Ktot + ch * 8;

  unsigned short* AsmDst0 = Asm + (wave * 2 + 0) * 512;
  unsigned short* AsmDst1 = Asm + (wave * 2 + 1) * 512;
  unsigned short* BsmDst0 = Bsm + (wave * 2 + 0) * 512;
  unsigned short* BsmDst1 = Bsm + (wave * 2 + 1) * 512;

  f32x4 acc[4][4];
#pragma unroll
  for (int m = 0; m < 4; ++m)
#pragma unroll
    for (int n = 0; n < 4; ++n) acc[m][n] = (f32x4){0.f, 0.f, 0.f, 0.f};

  for (int k0 = 0; k0 < Ktot; k0 += 32) {
    __syncthreads();   // previous tile's LDS reads complete
    gload16(apA0 + k0, AsmDst0);
    gload16(apA1 + k0, AsmDst1);
    gload16(bp0 + k0, BsmDst0);
    gload16(bp1 + k0, BsmDst1);
    __syncthreads();   // drains vmcnt (global_load_lds)

    s16x8 af[4], bfv[4];
#pragma unroll
    for (int m = 0; m < 4; ++m)
      af[m] = *(const s16x8*)(Asm + (wm * 64 + m * 16 + la) * 32 + hb * 8);
#pragma unroll
    for (int n = 0; n < 4; ++n)
      bfv[n] = *(const s16x8*)(Bsm + (wn * 64 + n * 16 + la) * 32 + hb * 8);
#pragma unroll
    for (int m = 0; m < 4; ++m)
#pragma unroll
      for (int n = 0; n < 4; ++n)
        acc[m][n] = __builtin_amdgcn_mfma_f32_16x16x32_bf16(af[m], bfv[n], acc[m][n], 0, 0, 0);
  }

  // Epilogue. C/D layout: col = lane&15, row = (lane>>4)*4 + j  [m89-verified]
#pragma unroll
  for (int m = 0; m < 4; ++m) {
#pragma unroll
    for (int n = 0; n < 4; ++n) {
      int gcol = ncol0 + wn * 64 + n * 16 + la;
      float bcst = bi[gcol];
#pragma unroll
      for (int j = 0; j < 4; ++j) {
        int lrow = wm * 64 + m * 16 + (hb << 2) + j;
        if (GROUPED && lrow >= rowcnt) continue;
        int prow = row0 + lrow;
        float v = acc[m][n][j] + bcst;
        if constexpr (EPI == EPI_GELU) {
          float ge = 0.5f * v * (1.0f + erff(v * 0.70710678118654752f));
          ((unsigned short*)OutP)[(size_t)prow * Nw + gcol] = f2bf(ge);
        } else if constexpr (EPI == EPI_SIG) {
          float s = 1.0f / (1.0f + expf(-v));
          ((unsigned short*)OutP)[(size_t)prow * Nw + gcol] = f2bf(s);
        } else {
          int orow = GATHER_OUT ? perm[prow] : prow;
          float gf = bf2f(G[(size_t)prow * Nw + gcol]);
          float xv = X[(size_t)orow * Nw + gcol];
          float res = xv + gf * v;
          float* op = (float*)OutP + (size_t)orow * Nw + gcol;
          if constexpr (ACCUM) *op += res; else *op = res;
        }
      }
    }
  }
}

// ---------------- launcher ----------------
// ws layout (bytes):
//   [0,   16MB)   xb : x as bf16             8192*1024*2
//   [16MB,80MB)   h1 : gelu output bf16      8192*4096*2   (reused shared->domain)
//   [80MB,96MB)   g  : gate bf16             8192*1024*2   (reused shared->domain)
//   [96MB,176MB)  wT : transposed bf16 weights, reused per-GEMM (max dW1/dW2 = 80MB)
//   [176MB,+34KB) meta: counts/cursor/tcnt/tiles/perm
// total ~176.04 MB

extern "C" void kernel_launch(void* const* d_in, const int* in_sizes, int n_in,
                              void* d_out, int out_size, void* d_ws, size_t ws_size,
                              hipStream_t stream) {
  const float* x   = (const float*)d_in[0];
  const int*   dom = (const int*)d_in[1];
  const float* sW1 = (const float*)d_in[2];
  const float* sb1 = (const float*)d_in[3];
  const float* sW2 = (const float*)d_in[4];
  const float* sb2 = (const float*)d_in[5];
  const float* sWg = (const float*)d_in[6];
  const float* sbg = (const float*)d_in[7];
  const float* dW1 = (const float*)d_in[8];
  const float* db1 = (const float*)d_in[9];
  const float* dW2 = (const float*)d_in[10];
  const float* db2 = (const float*)d_in[11];
  const float* dWg = (const float*)d_in[12];
  const float* dbg = (const float*)d_in[13];
  float* out = (float*)d_out;

  uint8_t* ws = (uint8_t*)d_ws;
  unsigned short* xb = (unsigned short*)ws;
  unsigned short* h1 = (unsigned short*)(ws + (size_t)16 * 1024 * 1024);
  unsigned short* g  = (unsigned short*)(ws + (size_t)80 * 1024 * 1024);
  unsigned short* wT = (unsigned short*)(ws + (size_t)96 * 1024 * 1024);
  int* meta   = (int*)(ws + (size_t)176 * 1024 * 1024);
  int* counts = meta;
  int* cursor = meta + 16;
  int* tcnt   = meta + 32;
  int4* tiles = (int4*)(meta + 48);
  int* perm   = meta + 48 + 4 * 80;

  k_prep0  <<<1, 64, 0, stream>>>(meta);
  k_count  <<<NTOK / 256, 256, 0, stream>>>(dom, counts);
  k_scan   <<<1, 1, 0, stream>>>(counts, cursor, tiles, tcnt);
  k_scatter<<<NTOK / 256, 256, 0, stream>>>(dom, cursor, perm);
  k_cvt    <<<NTOK * DIMK / 8 / 256, 256, 0, stream>>>(x, xb);

  dim3 blk(256);

  // ---- shared expert ----
  k_cvtT<<<dim3(DIMK / 64, FFNK / 64, 1), blk, 0, stream>>>(sW1, wT, DIMK, FFNK);
  gemm_k<EPI_GELU, false, false, false, false><<<dim3(64, 32), blk, 0, stream>>>(
      xb, DIMK, DIMK, wT, sb1, FFNK, nullptr, nullptr, h1, nullptr, nullptr, nullptr);

  k_cvtT<<<dim3(DIMK / 64, DIMK / 64, 1), blk, 0, stream>>>(sWg, wT, DIMK, DIMK);
  gemm_k<EPI_SIG, false, false, false, false><<<dim3(64, 8), blk, 0, stream>>>(
      xb, DIMK, DIMK, wT, sbg, DIMK, nullptr, nullptr, g, nullptr, nullptr, nullptr);

  k_cvtT<<<dim3(FFNK / 64, DIMK / 64, 1), blk, 0, stream>>>(sW2, wT, FFNK, DIMK);
  gemm_k<EPI_OUT, false, false, false, false><<<dim3(64, 8), blk, 0, stream>>>(
      h1, FFNK, FFNK, wT, sb2, DIMK, x, g, out, nullptr, nullptr, nullptr);

  // ---- domain experts (grouped via tile table, rows gathered through perm) ----
  k_cvtT<<<dim3(DIMK / 64, FFNK / 64, NEXP), blk, 0, stream>>>(dW1, wT, DIMK, FFNK);
  gemm_k<EPI_GELU, true, true, false, false><<<dim3(MAXTILES, 32), blk, 0, stream>>>(
      xb, DIMK, DIMK, wT, db1, FFNK, nullptr, nullptr, h1, perm, tiles, tcnt);

  k_cvtT<<<dim3(DIMK / 64, DIMK / 64, NEXP), blk, 0, stream>>>(dWg, wT, DIMK, DIMK);
  gemm_k<EPI_SIG, true, true, false, false><<<dim3(MAXTILES, 8), blk, 0, stream>>>(
      xb, DIMK, DIMK, wT, dbg, DIMK, nullptr, nullptr, g, perm, tiles, tcnt);

  k_cvtT<<<dim3(FFNK / 64, DIMK / 64, NEXP), blk, 0, stream>>>(dW2, wT, FFNK, DIMK);
  gemm_k<EPI_OUT, true, false, true, true><<<dim3(MAXTILES, 8), blk, 0, stream>>>(
      h1, FFNK, FFNK, wT, db2, DIMK, x, g, out, perm, tiles, tcnt);
}